// Round 1
// baseline (598.825 us; speedup 1.0000x reference)
//
#include <hip/hip_runtime.h>

// Problem constants
#define NNODE 50000
#define NEDGE 400000
// IN=256, H=128, D=64, K=8

// ---------------- workspace layout (bytes) ----------------
#define OFF_SUMS    0x0000     // 256 f
#define OFF_SUMSQ   0x0400     // 256 f
#define OFF_SCALE   0x0800     // 256 f
#define OFF_SHIFT   0x0C00     // 256 f
#define OFF_CSHIFT  0x1000     // 128 f
#define OFF_PART    0x1400     // 64 i (scan partials)
#define OFF_BPREF   0x1600     // 64 i (scan block prefix)
#define OFF_W1P     0x2000     // 256*128 f   -> ends 0x22000
#define OFF_WT2     0x22000    // 64*512 f    -> ends 0x42000
#define OFF_DEG     0x42000    // 50000 i
#define OFF_OFFS    0x73000    // 50001 i
#define OFF_CURS    0xA4000    // 50000 i
#define OFF_DINV    0xD5000    // 50000 f
#define OFF_CSR     0x106000   // 400000 i (src node per sorted edge)
#define OFF_CSRE    0x290000   // 400000 i (orig edge id per sorted edge)
#define OFF_LV      0x420000   // 50000*16 f  -> ends 0x72D400
#define OFF_H0      0x800000   // 50000*128 f (25.6MB)   -> ends 0x2068000
#define OFF_Z0      OFF_H0                 // reuse (h0 dead): 50000*64 f
#define OFF_Z       (OFF_H0 + 0xD00000)    // 50000*64 f, ends < 0x2100000
#define OFF_H1      0x2100000  // 50000*128 f (25.6MB)
#define OFF_Q       OFF_H1                 // reuse (h1 dead): 50000*512 bf16 (51.2MB)

static __device__ __forceinline__ unsigned short f32_to_bf16(float f) {
  unsigned int u = __float_as_uint(f);
  u += 0x7fffu + ((u >> 16) & 1u);          // round-to-nearest-even
  return (unsigned short)(u >> 16);
}

// ---------------- BatchNorm statistics ----------------
__global__ __launch_bounds__(256) void bn_stats(const float* __restrict__ x,
                                                float* __restrict__ sums,
                                                float* __restrict__ sumsq) {
  const int t = threadIdx.x;                 // column 0..255
  const int per = (NNODE + gridDim.x - 1) / gridDim.x;
  const int r0 = blockIdx.x * per;
  const int r1 = min(NNODE, r0 + per);
  float s = 0.f, q = 0.f;
  for (int r = r0; r < r1; ++r) {
    float v = x[(size_t)r * 256 + t];
    s += v; q += v * v;
  }
  atomicAdd(&sums[t], s);
  atomicAdd(&sumsq[t], q);
}

__global__ void bn_finalize(const float* __restrict__ sums, const float* __restrict__ sumsq,
                            const float* __restrict__ gamma, const float* __restrict__ beta,
                            float* __restrict__ scale, float* __restrict__ shift) {
  const int i = threadIdx.x;                 // 256 threads
  float mean = sums[i] * (1.f / NNODE);
  float var  = sumsq[i] * (1.f / NNODE) - mean * mean;
  float sc   = rsqrtf(var + 1e-5f) * gamma[i];
  scale[i] = sc;
  shift[i] = beta[i] - mean * sc;
}

__global__ void make_w1p(const float* __restrict__ W1, const float* __restrict__ scale,
                         float* __restrict__ W1p) {
  const int idx = blockIdx.x * 256 + threadIdx.x;   // 32768
  W1p[idx] = scale[idx >> 7] * W1[idx];             // 128 cols
}

__global__ void make_cshift(const float* __restrict__ W1, const float* __restrict__ shift,
                            float* __restrict__ cshift) {
  const int j = threadIdx.x;                 // 128 threads
  float s = 0.f;
  for (int i = 0; i < 256; ++i) s += shift[i] * W1[i * 128 + j];
  cshift[j] = s;
}

// Wt[d][c][k] -> Wt2[c][d*8+k]  (B matrix for the q-GEMM)
__global__ void make_wt2(const float* __restrict__ Wt, float* __restrict__ Wt2) {
  const int idx = blockIdx.x * 256 + threadIdx.x;   // 32768
  const int d = idx >> 9, ck = idx & 511;
  const int c = ck >> 3, k = ck & 7;
  Wt2[c * 512 + d * 8 + k] = Wt[idx];
}

// ---------------- degree / CSR build ----------------
__global__ __launch_bounds__(256) void count_deg(const int* __restrict__ col, int* __restrict__ deg) {
  const int e = blockIdx.x * 256 + threadIdx.x;
  if (e < NEDGE) atomicAdd(&deg[col[e]], 1);
}

__global__ __launch_bounds__(1024) void scan_a(const int* __restrict__ deg, int* __restrict__ offs,
                                               int* __restrict__ partials, float* __restrict__ dinv) {
  __shared__ int buf[1024];
  const int t = threadIdx.x;
  const int i = blockIdx.x * 1024 + t;
  const int v = (i < NNODE) ? deg[i] : 0;
  buf[t] = v;
  __syncthreads();
  for (int off = 1; off < 1024; off <<= 1) {
    int a = (t >= off) ? buf[t - off] : 0;
    __syncthreads();
    buf[t] += a;
    __syncthreads();
  }
  if (i < NNODE) {
    offs[i] = buf[t] - v;                     // block-local exclusive
    dinv[i] = rsqrtf((float)(v + 1));         // +1 self loop
  }
  if (t == 1023) partials[blockIdx.x] = buf[t];
}

__global__ void scan_b(const int* __restrict__ partials, int* __restrict__ bpref,
                       int* __restrict__ offs) {
  if (threadIdx.x == 0) {
    int run = 0;
    for (int b = 0; b < 49; ++b) { bpref[b] = run; run += partials[b]; }
    offs[NNODE] = run;                        // == NEDGE
  }
}

__global__ __launch_bounds__(1024) void scan_c(int* __restrict__ offs, const int* __restrict__ bpref,
                                               int* __restrict__ cursor) {
  const int i = blockIdx.x * 1024 + threadIdx.x;
  if (i < NNODE) {
    int o = offs[i] + bpref[blockIdx.x];
    offs[i] = o;
    cursor[i] = o;
  }
}

__global__ __launch_bounds__(256) void fill_csr(const int* __restrict__ row, const int* __restrict__ col,
                                                int* __restrict__ cursor, int* __restrict__ csr_src,
                                                int* __restrict__ csr_eid) {
  const int e = blockIdx.x * 256 + threadIdx.x;
  if (e < NEDGE) {
    int c = col[e];
    int p = atomicAdd(&cursor[c], 1);
    csr_src[p] = row[e];
    csr_eid[p] = e;
  }
}

// ---------------- tiled fp32 GEMM:  C[M,Nd] = A[M,Kd] @ B[Kd,Nd] (+bias) ----------------
template <int BM, int BN, int BK, int TM, int TN, bool BF16OUT>
__global__ __launch_bounds__(256) void gemm_tiled(const float* __restrict__ A,
                                                  const float* __restrict__ B,
                                                  void* __restrict__ Cout,
                                                  const float* __restrict__ bias,
                                                  int M, int Kd, int Nd) {
  constexpr int TX = BN / TN;
  constexpr int TY = BM / TM;
  constexpr int THREADS = TX * TY;            // 256
  __shared__ __align__(16) float As[BM][BK + 4];
  __shared__ __align__(16) float Bs[BK][BN];
  const int tid = threadIdx.x;
  const int tx = tid % TX, ty = tid / TX;
  const int m0 = blockIdx.x * BM, n0 = blockIdx.y * BN;

  float acc[TM][TN];
  for (int i = 0; i < TM; ++i)
    for (int j = 0; j < TN; ++j) acc[i][j] = 0.f;

  for (int k0 = 0; k0 < Kd; k0 += BK) {
    for (int i = tid; i < (BM * BK) / 4; i += THREADS) {
      int mm = i / (BK / 4), kq = i % (BK / 4);
      int gm = m0 + mm;
      float4 v = make_float4(0.f, 0.f, 0.f, 0.f);
      if (gm < M) v = *(const float4*)(A + (size_t)gm * Kd + k0 + kq * 4);
      *(float4*)(&As[mm][kq * 4]) = v;
    }
    for (int i = tid; i < (BK * BN) / 4; i += THREADS) {
      int kk = i / (BN / 4), nq = i % (BN / 4);
      *(float4*)(&Bs[kk][nq * 4]) = *(const float4*)(B + (size_t)(k0 + kk) * Nd + n0 + nq * 4);
    }
    __syncthreads();
#pragma unroll
    for (int kk = 0; kk < BK; ++kk) {
      float a[TM], b[TN];
#pragma unroll
      for (int i = 0; i < TM; ++i) a[i] = As[ty * TM + i][kk];
#pragma unroll
      for (int j4 = 0; j4 < TN / 4; ++j4) {
        float4 bv = *(const float4*)(&Bs[kk][tx * TN + j4 * 4]);
        b[j4 * 4 + 0] = bv.x; b[j4 * 4 + 1] = bv.y; b[j4 * 4 + 2] = bv.z; b[j4 * 4 + 3] = bv.w;
      }
#pragma unroll
      for (int i = 0; i < TM; ++i)
#pragma unroll
        for (int j = 0; j < TN; ++j) acc[i][j] = fmaf(a[i], b[j], acc[i][j]);
    }
    __syncthreads();
  }

  float bv[TN];
#pragma unroll
  for (int j = 0; j < TN; ++j) bv[j] = bias ? bias[n0 + tx * TN + j] : 0.f;

#pragma unroll
  for (int i = 0; i < TM; ++i) {
    int gm = m0 + ty * TM + i;
    if (gm >= M) continue;
    if constexpr (BF16OUT) {
      unsigned short* C = (unsigned short*)Cout;
      alignas(16) unsigned short tmp[TN];
#pragma unroll
      for (int j = 0; j < TN; ++j) tmp[j] = f32_to_bf16(acc[i][j] + bv[j]);
      if constexpr (TN == 8) {
        *(uint4*)(C + (size_t)gm * Nd + n0 + tx * TN) = *(const uint4*)tmp;
      } else {
#pragma unroll
        for (int j = 0; j < TN; ++j) C[(size_t)gm * Nd + n0 + tx * TN + j] = tmp[j];
      }
    } else {
      float* C = (float*)Cout;
#pragma unroll
      for (int j4 = 0; j4 < TN / 4; ++j4) {
        float4 v;
        v.x = acc[i][j4 * 4 + 0] + bv[j4 * 4 + 0];
        v.y = acc[i][j4 * 4 + 1] + bv[j4 * 4 + 1];
        v.z = acc[i][j4 * 4 + 2] + bv[j4 * 4 + 2];
        v.w = acc[i][j4 * 4 + 3] + bv[j4 * 4 + 3];
        *(float4*)(C + (size_t)gm * Nd + n0 + tx * TN + j4 * 4) = v;
      }
    }
  }
}

// ---------------- GCN aggregation: out[v] = dinv[v]*(sum_in h[r]*dinv[r] + h[v]*dinv[v]) + b ----------------
template <int F, bool LEAKY>
__global__ __launch_bounds__(256) void agg_kernel(const float* __restrict__ h,
                                                  const int* __restrict__ csr_src,
                                                  const int* __restrict__ offs,
                                                  const float* __restrict__ dinv,
                                                  const float* __restrict__ bias,
                                                  float* __restrict__ out) {
  constexpr int NPB = 256 / F;
  const int v = blockIdx.x * NPB + threadIdx.x / F;
  const int f = threadIdx.x % F;
  if (v >= NNODE) return;
  const float dv = dinv[v];
  float acc = h[(size_t)v * F + f] * dv;      // self loop (x dv again below)
  const int j0 = offs[v], j1 = offs[v + 1];
  for (int j = j0; j < j1; ++j) {
    int r = csr_src[j];
    acc = fmaf(h[(size_t)r * F + f], dinv[r], acc);
  }
  float o = acc * dv + bias[f];
  if (LEAKY) o = (o >= 0.f) ? o : 0.1f * o;
  out[(size_t)v * F + f] = o;
}

// ---------------- per-node linear terms: LV[v][k]=z_v.V[k,:64], LV[v][8+k]=z_v.V[k,64:] ----------------
__global__ __launch_bounds__(256) void lv_kernel(const float* __restrict__ z,
                                                 const float* __restrict__ V,
                                                 float* __restrict__ LV) {
  const int idx = blockIdx.x * 256 + threadIdx.x;     // 800000
  if (idx >= NNODE * 16) return;
  const int v = idx >> 4, kk = idx & 15;
  const float* vr = V + (kk & 7) * 128 + ((kk & 8) ? 64 : 0);
  const float* zr = z + (size_t)v * 64;
  float s = 0.f;
#pragma unroll
  for (int d4 = 0; d4 < 16; ++d4) {
    float4 zv = *(const float4*)(zr + d4 * 4);
    float4 vv = *(const float4*)(vr + d4 * 4);
    s += zv.x * vv.x + zv.y * vv.y + zv.z * vv.z + zv.w * vv.w;
  }
  LV[idx] = s;
}

// ---------------- decode: wave per dst node; 8 edges x 8 k-lanes ----------------
__global__ __launch_bounds__(256) void decode_kernel(const int* __restrict__ csr_src,
                                                     const int* __restrict__ csr_eid,
                                                     const int* __restrict__ offs,
                                                     const float* __restrict__ z,
                                                     const unsigned short* __restrict__ Q,  // bf16 bits
                                                     const float* __restrict__ LV,
                                                     const float* __restrict__ bt,
                                                     const float* __restrict__ U,
                                                     float* __restrict__ out) {
  __shared__ float qs[4][512];
  const int w = threadIdx.x >> 6, lane = threadIdx.x & 63;
  const int v = blockIdx.x * 4 + w;                 // 12500*4 == 50000 exactly

  { // stage q_v (bf16 -> f32) into LDS: lane loads 16B = 8 bf16
    const unsigned short* qrow = Q + (size_t)v * 512;
    union { uint4 r; unsigned short u[8]; } uu;
    uu.r = *(const uint4*)(qrow + lane * 8);
#pragma unroll
    for (int j = 0; j < 8; ++j)
      qs[w][lane * 8 + j] = __uint_as_float(((unsigned int)uu.u[j]) << 16);
  }
  __syncthreads();

  const int g = lane >> 3, k = lane & 7;
  const float uk = U[k];
  const float lvc = LV[(size_t)v * 16 + 8 + k] + bt[k];
  const int j0 = offs[v], j1 = offs[v + 1];

  for (int jb = j0; jb < j1; jb += 8) {
    const int j = jb + g;
    const bool act = (j < j1);
    const int r = act ? csr_src[j] : 0;
    const int eid = act ? csr_eid[j] : 0;
    const float4* zr = (const float4*)(z + (size_t)r * 64);
    float acc = 0.f;
#pragma unroll
    for (int d4 = 0; d4 < 16; ++d4) {
      float4 zv = zr[d4];
      const float* qp = &qs[w][d4 * 32 + k];
      acc = fmaf(zv.x, qp[0], acc);
      acc = fmaf(zv.y, qp[8], acc);
      acc = fmaf(zv.z, qp[16], acc);
      acc = fmaf(zv.w, qp[24], acc);
    }
    acc += LV[(size_t)r * 16 + k] + lvc;
    float c = tanhf(acc) * uk;
    c += __shfl_xor(c, 1);
    c += __shfl_xor(c, 2);
    c += __shfl_xor(c, 4);
    if (act && k == 0) out[eid] = 1.f / (1.f + __expf(-c));
  }
}

// ---------------- host launch ----------------
extern "C" void kernel_launch(void* const* d_in, const int* in_sizes, int n_in,
                              void* d_out, int out_size, void* d_ws, size_t ws_size,
                              hipStream_t stream) {
  const float* x     = (const float*)d_in[0];
  const int*   ei    = (const int*)d_in[1];
  const float* gamma = (const float*)d_in[2];
  const float* beta  = (const float*)d_in[3];
  const float* W1    = (const float*)d_in[4];
  const float* b1    = (const float*)d_in[5];
  const float* W2    = (const float*)d_in[6];
  const float* b2    = (const float*)d_in[7];
  const float* Wt    = (const float*)d_in[8];
  const float* V     = (const float*)d_in[9];
  const float* bt    = (const float*)d_in[10];
  const float* U     = (const float*)d_in[11];
  float* out = (float*)d_out;
  char* ws = (char*)d_ws;

  const int* row = ei;
  const int* col = ei + NEDGE;

  float* sums   = (float*)(ws + OFF_SUMS);
  float* sumsq  = (float*)(ws + OFF_SUMSQ);
  float* scale  = (float*)(ws + OFF_SCALE);
  float* shiftv = (float*)(ws + OFF_SHIFT);
  float* cshift = (float*)(ws + OFF_CSHIFT);
  int*   part   = (int*)(ws + OFF_PART);
  int*   bpref  = (int*)(ws + OFF_BPREF);
  float* W1p    = (float*)(ws + OFF_W1P);
  float* Wt2    = (float*)(ws + OFF_WT2);
  int*   deg    = (int*)(ws + OFF_DEG);
  int*   offs   = (int*)(ws + OFF_OFFS);
  int*   curs   = (int*)(ws + OFF_CURS);
  float* dinv   = (float*)(ws + OFF_DINV);
  int*   csr    = (int*)(ws + OFF_CSR);
  int*   csre   = (int*)(ws + OFF_CSRE);
  float* LV     = (float*)(ws + OFF_LV);
  float* h0     = (float*)(ws + OFF_H0);
  float* h1     = (float*)(ws + OFF_H1);
  float* z0     = (float*)(ws + OFF_Z0);
  float* zz     = (float*)(ws + OFF_Z);
  unsigned short* Q = (unsigned short*)(ws + OFF_Q);

  hipMemsetAsync(ws + OFF_SUMS, 0, 0x800, stream);        // sums+sumsq
  hipMemsetAsync(ws + OFF_DEG, 0, NNODE * 4, stream);

  bn_stats<<<256, 256, 0, stream>>>(x, sums, sumsq);
  count_deg<<<1563, 256, 0, stream>>>(col, deg);
  bn_finalize<<<1, 256, 0, stream>>>(sums, sumsq, gamma, beta, scale, shiftv);
  make_w1p<<<128, 256, 0, stream>>>(W1, scale, W1p);
  make_cshift<<<1, 128, 0, stream>>>(W1, shiftv, cshift);
  make_wt2<<<128, 256, 0, stream>>>(Wt, Wt2);

  scan_a<<<49, 1024, 0, stream>>>(deg, offs, part, dinv);
  scan_b<<<1, 64, 0, stream>>>(part, bpref, offs);
  scan_c<<<49, 1024, 0, stream>>>(offs, bpref, curs);
  fill_csr<<<1563, 256, 0, stream>>>(row, col, curs, csr, csre);

  // encode
  gemm_tiled<64, 128, 32, 4, 8, false><<<dim3(782, 1), 256, 0, stream>>>(x, W1p, h0, cshift, NNODE, 256, 128);
  agg_kernel<128, true><<<25000, 256, 0, stream>>>(h0, csr, offs, dinv, b1, h1);
  gemm_tiled<64, 64, 32, 4, 4, false><<<dim3(782, 1), 256, 0, stream>>>(h1, W2, z0, nullptr, NNODE, 128, 64);
  agg_kernel<64, false><<<12500, 256, 0, stream>>>(z0, csr, offs, dinv, b2, zz);

  // decode precompute
  gemm_tiled<64, 128, 32, 4, 8, true><<<dim3(782, 4), 256, 0, stream>>>(zz, Wt2, Q, nullptr, NNODE, 64, 512);
  lv_kernel<<<3125, 256, 0, stream>>>(zz, V, LV);

  // per-edge decode
  decode_kernel<<<12500, 256, 0, stream>>>(csr, csre, offs, zz, Q, LV, bt, U, out);
}

// Round 3
// 530.637 us; speedup vs baseline: 1.1285x; 1.1285x over previous
//
#include <hip/hip_runtime.h>

// Problem constants
#define NNODE 50000
#define NEDGE 400000
// IN=256, H=128, D=64, K=8

// ---------------- workspace layout (bytes) ----------------
#define OFF_SUMS    0x0000     // 256 f
#define OFF_SUMSQ   0x0400     // 256 f
#define OFF_SCALE   0x0800     // 256 f
#define OFF_SHIFT   0x0C00     // 256 f
#define OFF_CSHIFT  0x1000     // 128 f
#define OFF_PART    0x1400     // 64 i (scan partials)
#define OFF_BPREF   0x1600     // 64 i (scan block prefix)
#define OFF_W1P     0x2000     // 256*128 f   -> ends 0x22000
#define OFF_WT2     0x22000    // 64*512 f    -> ends 0x42000
#define OFF_DEG     0x42000    // 50000 i
#define OFF_OFFS    0x73000    // 50001 i
#define OFF_CURS    0xA4000    // 50000 i
#define OFF_DINV    0xD5000    // 50000 f
#define OFF_CSR     0x106000   // 400000 i (src node per sorted edge)
#define OFF_CSRE    0x290000   // 400000 i (orig edge id per sorted edge)
#define OFF_LV      0x420000   // 50000*16 f  -> ends 0x72D400
#define OFF_H0      0x800000   // 50000*128 f (25.6MB)   -> ends 0x2068000
#define OFF_Z0      OFF_H0                 // reuse (h0 dead): 50000*64 f
#define OFF_Z       (OFF_H0 + 0xD00000)    // 50000*64 f, ends < 0x2100000
#define OFF_H1      0x2100000  // 50000*128 f (25.6MB)
#define OFF_Q       OFF_H1                 // reuse (h1 dead): 50000*512 bf16 (51.2MB)

static __device__ __forceinline__ unsigned short f32_to_bf16(float f) {
  unsigned int u = __float_as_uint(f);
  u += 0x7fffu + ((u >> 16) & 1u);          // round-to-nearest-even
  return (unsigned short)(u >> 16);
}

// ---------------- BatchNorm statistics ----------------
__global__ __launch_bounds__(256) void bn_stats(const float* __restrict__ x,
                                                float* __restrict__ sums,
                                                float* __restrict__ sumsq) {
  const int t = threadIdx.x;                 // column 0..255
  const int per = (NNODE + gridDim.x - 1) / gridDim.x;
  const int r0 = blockIdx.x * per;
  const int r1 = min(NNODE, r0 + per);
  float s = 0.f, q = 0.f;
  for (int r = r0; r < r1; ++r) {
    float v = x[(size_t)r * 256 + t];
    s += v; q += v * v;
  }
  atomicAdd(&sums[t], s);
  atomicAdd(&sumsq[t], q);
}

__global__ void bn_finalize(const float* __restrict__ sums, const float* __restrict__ sumsq,
                            const float* __restrict__ gamma, const float* __restrict__ beta,
                            float* __restrict__ scale, float* __restrict__ shift) {
  const int i = threadIdx.x;                 // 256 threads
  float mean = sums[i] * (1.f / NNODE);
  float var  = sumsq[i] * (1.f / NNODE) - mean * mean;
  float sc   = rsqrtf(var + 1e-5f) * gamma[i];
  scale[i] = sc;
  shift[i] = beta[i] - mean * sc;
}

__global__ void make_w1p(const float* __restrict__ W1, const float* __restrict__ scale,
                         float* __restrict__ W1p) {
  const int idx = blockIdx.x * 256 + threadIdx.x;   // 32768
  W1p[idx] = scale[idx >> 7] * W1[idx];             // 128 cols
}

__global__ void make_cshift(const float* __restrict__ W1, const float* __restrict__ shift,
                            float* __restrict__ cshift) {
  const int j = threadIdx.x;                 // 128 threads
  float s = 0.f;
  for (int i = 0; i < 256; ++i) s += shift[i] * W1[i * 128 + j];
  cshift[j] = s;
}

// Wt[d][c][k] -> Wt2[c][d*8+k]  (B matrix for the q-GEMM)
__global__ void make_wt2(const float* __restrict__ Wt, float* __restrict__ Wt2) {
  const int idx = blockIdx.x * 256 + threadIdx.x;   // 32768
  const int d = idx >> 9, ck = idx & 511;
  const int c = ck >> 3, k = ck & 7;
  Wt2[c * 512 + d * 8 + k] = Wt[idx];
}

// ---------------- degree / CSR build ----------------
__global__ __launch_bounds__(256) void count_deg(const int* __restrict__ col, int* __restrict__ deg) {
  const int e = blockIdx.x * 256 + threadIdx.x;
  if (e < NEDGE) atomicAdd(&deg[col[e]], 1);
}

__global__ __launch_bounds__(1024) void scan_a(const int* __restrict__ deg, int* __restrict__ offs,
                                               int* __restrict__ partials, float* __restrict__ dinv) {
  __shared__ int buf[1024];
  const int t = threadIdx.x;
  const int i = blockIdx.x * 1024 + t;
  const int v = (i < NNODE) ? deg[i] : 0;
  buf[t] = v;
  __syncthreads();
  for (int off = 1; off < 1024; off <<= 1) {
    int a = (t >= off) ? buf[t - off] : 0;
    __syncthreads();
    buf[t] += a;
    __syncthreads();
  }
  if (i < NNODE) {
    offs[i] = buf[t] - v;                     // block-local exclusive
    dinv[i] = rsqrtf((float)(v + 1));         // +1 self loop
  }
  if (t == 1023) partials[blockIdx.x] = buf[t];
}

__global__ void scan_b(const int* __restrict__ partials, int* __restrict__ bpref,
                       int* __restrict__ offs) {
  if (threadIdx.x == 0) {
    int run = 0;
    for (int b = 0; b < 49; ++b) { bpref[b] = run; run += partials[b]; }
    offs[NNODE] = run;                        // == NEDGE
  }
}

__global__ __launch_bounds__(1024) void scan_c(int* __restrict__ offs, const int* __restrict__ bpref,
                                               int* __restrict__ cursor) {
  const int i = blockIdx.x * 1024 + threadIdx.x;
  if (i < NNODE) {
    int o = offs[i] + bpref[blockIdx.x];
    offs[i] = o;
    cursor[i] = o;
  }
}

__global__ __launch_bounds__(256) void fill_csr(const int* __restrict__ row, const int* __restrict__ col,
                                                int* __restrict__ cursor, int* __restrict__ csr_src,
                                                int* __restrict__ csr_eid) {
  const int e = blockIdx.x * 256 + threadIdx.x;
  if (e < NEDGE) {
    int c = col[e];
    int p = atomicAdd(&cursor[c], 1);
    csr_src[p] = row[e];
    csr_eid[p] = e;
  }
}

// ---------------- tiled fp32 GEMM:  C[M,Nd] = (A[M,Kd] @ B[Kd,Nd] + bias) * rowscale ----------------
template <int BM, int BN, int BK, int TM, int TN, bool BF16OUT>
__global__ __launch_bounds__(256) void gemm_tiled(const float* __restrict__ A,
                                                  const float* __restrict__ B,
                                                  void* __restrict__ Cout,
                                                  const float* __restrict__ bias,
                                                  const float* __restrict__ rowscale,
                                                  int M, int Kd, int Nd) {
  constexpr int TX = BN / TN;
  constexpr int TY = BM / TM;
  constexpr int THREADS = TX * TY;            // 256
  __shared__ __align__(16) float As[BM][BK + 4];
  __shared__ __align__(16) float Bs[BK][BN];
  const int tid = threadIdx.x;
  const int tx = tid % TX, ty = tid / TX;
  const int m0 = blockIdx.x * BM, n0 = blockIdx.y * BN;

  float acc[TM][TN];
  for (int i = 0; i < TM; ++i)
    for (int j = 0; j < TN; ++j) acc[i][j] = 0.f;

  for (int k0 = 0; k0 < Kd; k0 += BK) {
    for (int i = tid; i < (BM * BK) / 4; i += THREADS) {
      int mm = i / (BK / 4), kq = i % (BK / 4);
      int gm = m0 + mm;
      float4 v = make_float4(0.f, 0.f, 0.f, 0.f);
      if (gm < M) v = *(const float4*)(A + (size_t)gm * Kd + k0 + kq * 4);
      *(float4*)(&As[mm][kq * 4]) = v;
    }
    for (int i = tid; i < (BK * BN) / 4; i += THREADS) {
      int kk = i / (BN / 4), nq = i % (BN / 4);
      *(float4*)(&Bs[kk][nq * 4]) = *(const float4*)(B + (size_t)(k0 + kk) * Nd + n0 + nq * 4);
    }
    __syncthreads();
#pragma unroll
    for (int kk = 0; kk < BK; ++kk) {
      float a[TM], b[TN];
#pragma unroll
      for (int i = 0; i < TM; ++i) a[i] = As[ty * TM + i][kk];
#pragma unroll
      for (int j4 = 0; j4 < TN / 4; ++j4) {
        float4 bv = *(const float4*)(&Bs[kk][tx * TN + j4 * 4]);
        b[j4 * 4 + 0] = bv.x; b[j4 * 4 + 1] = bv.y; b[j4 * 4 + 2] = bv.z; b[j4 * 4 + 3] = bv.w;
      }
#pragma unroll
      for (int i = 0; i < TM; ++i)
#pragma unroll
        for (int j = 0; j < TN; ++j) acc[i][j] = fmaf(a[i], b[j], acc[i][j]);
    }
    __syncthreads();
  }

  float bv[TN];
#pragma unroll
  for (int j = 0; j < TN; ++j) bv[j] = bias ? bias[n0 + tx * TN + j] : 0.f;

#pragma unroll
  for (int i = 0; i < TM; ++i) {
    int gm = m0 + ty * TM + i;
    if (gm >= M) continue;
    const float rs = rowscale ? rowscale[gm] : 1.f;
    if constexpr (BF16OUT) {
      unsigned short* C = (unsigned short*)Cout;
      alignas(16) unsigned short tmp[TN];
#pragma unroll
      for (int j = 0; j < TN; ++j) tmp[j] = f32_to_bf16((acc[i][j] + bv[j]) * rs);
      if constexpr (TN == 8) {
        *(uint4*)(C + (size_t)gm * Nd + n0 + tx * TN) = *(const uint4*)tmp;
      } else {
#pragma unroll
        for (int j = 0; j < TN; ++j) C[(size_t)gm * Nd + n0 + tx * TN + j] = tmp[j];
      }
    } else {
      float* C = (float*)Cout;
#pragma unroll
      for (int j4 = 0; j4 < TN / 4; ++j4) {
        float4 v;
        v.x = (acc[i][j4 * 4 + 0] + bv[j4 * 4 + 0]) * rs;
        v.y = (acc[i][j4 * 4 + 1] + bv[j4 * 4 + 1]) * rs;
        v.z = (acc[i][j4 * 4 + 2] + bv[j4 * 4 + 2]) * rs;
        v.w = (acc[i][j4 * 4 + 3] + bv[j4 * 4 + 3]) * rs;
        *(float4*)(C + (size_t)gm * Nd + n0 + tx * TN + j4 * 4) = v;
      }
    }
  }
}

// ---------------- GCN aggregation over pre-scaled features ----------------
// hs[r] = (feature row r) * dinv[r];  out[v] = dinv[v]*(sum_in hs[r] + hs[v]) + b
// 4-wide predicated unroll: 4 independent accumulators keep 4 row-gathers in flight.
template <int F, bool LEAKY>
__global__ __launch_bounds__(256) void agg_kernel(const float* __restrict__ hs,
                                                  const int* __restrict__ csr_src,
                                                  const int* __restrict__ offs,
                                                  const float* __restrict__ dinv,
                                                  const float* __restrict__ bias,
                                                  float* __restrict__ out) {
  constexpr int NPB = 256 / F;
  const int vth = blockIdx.x * NPB + threadIdx.x / F;
  const int v = __builtin_amdgcn_readfirstlane(vth);   // wave-uniform in both configs
  const int f = threadIdx.x % F;
  const float dv = dinv[v];
  const int j0 = offs[v], j1 = offs[v + 1];

  float a0 = hs[(size_t)v * F + f];           // self loop (pre-scaled by dinv[v])
  float a1 = 0.f, a2 = 0.f, a3 = 0.f;

  for (int jb = j0; jb < j1; jb += 4) {
    const int jm = j1 - 1;
    const int r0 = csr_src[jb];
    const int r1 = csr_src[min(jb + 1, jm)];
    const int r2 = csr_src[min(jb + 2, jm)];
    const int r3 = csr_src[min(jb + 3, jm)];
    const float w1 = (jb + 1 <= jm) ? 1.f : 0.f;
    const float w2 = (jb + 2 <= jm) ? 1.f : 0.f;
    const float w3 = (jb + 3 <= jm) ? 1.f : 0.f;
    a0 += hs[(size_t)r0 * F + f];
    a1 = fmaf(w1, hs[(size_t)r1 * F + f], a1);
    a2 = fmaf(w2, hs[(size_t)r2 * F + f], a2);
    a3 = fmaf(w3, hs[(size_t)r3 * F + f], a3);
  }

  float o = ((a0 + a1) + (a2 + a3)) * dv + bias[f];
  if (LEAKY) o = (o >= 0.f) ? o : 0.1f * o;
  out[(size_t)v * F + f] = o;
}

// ---------------- per-node linear terms: LV[v][k]=z_v.V[k,:64], LV[v][8+k]=z_v.V[k,64:] ----------------
__global__ __launch_bounds__(256) void lv_kernel(const float* __restrict__ z,
                                                 const float* __restrict__ V,
                                                 float* __restrict__ LV) {
  const int idx = blockIdx.x * 256 + threadIdx.x;     // 800000
  if (idx >= NNODE * 16) return;
  const int v = idx >> 4, kk = idx & 15;
  const float* vr = V + (kk & 7) * 128 + ((kk & 8) ? 64 : 0);
  const float* zr = z + (size_t)v * 64;
  float s = 0.f;
#pragma unroll
  for (int d4 = 0; d4 < 16; ++d4) {
    float4 zv = *(const float4*)(zr + d4 * 4);
    float4 vv = *(const float4*)(vr + d4 * 4);
    s += zv.x * vv.x + zv.y * vv.y + zv.z * vv.z + zv.w * vv.w;
  }
  LV[idx] = s;
}

// ---------------- decode: wave per dst node; 8 edges x 8 k-lanes ----------------
__global__ __launch_bounds__(256) void decode_kernel(const int* __restrict__ csr_src,
                                                     const int* __restrict__ csr_eid,
                                                     const int* __restrict__ offs,
                                                     const float* __restrict__ z,
                                                     const unsigned short* __restrict__ Q,  // bf16 bits
                                                     const float* __restrict__ LV,
                                                     const float* __restrict__ bt,
                                                     const float* __restrict__ U,
                                                     float* __restrict__ out) {
  __shared__ float qs[4][512];
  const int w = threadIdx.x >> 6, lane = threadIdx.x & 63;
  const int v = blockIdx.x * 4 + w;                 // 12500*4 == 50000 exactly

  { // stage q_v (bf16 -> f32) into LDS: lane loads 16B = 8 bf16
    const unsigned short* qrow = Q + (size_t)v * 512;
    union { uint4 r; unsigned short u[8]; } uu;
    uu.r = *(const uint4*)(qrow + lane * 8);
#pragma unroll
    for (int j = 0; j < 8; ++j)
      qs[w][lane * 8 + j] = __uint_as_float(((unsigned int)uu.u[j]) << 16);
  }
  __syncthreads();

  const int g = lane >> 3, k = lane & 7;
  const float uk = U[k];
  const float lvc = LV[(size_t)v * 16 + 8 + k] + bt[k];
  const int j0 = offs[v], j1 = offs[v + 1];

  for (int jb = j0; jb < j1; jb += 8) {
    const int j = jb + g;
    const bool act = (j < j1);
    const int r = act ? csr_src[j] : 0;
    const int eid = act ? csr_eid[j] : 0;
    const float4* zr = (const float4*)(z + (size_t)r * 64);
    float acc = 0.f;
#pragma unroll
    for (int d4 = 0; d4 < 16; ++d4) {
      float4 zv = zr[d4];
      const float* qp = &qs[w][d4 * 32 + k];
      acc = fmaf(zv.x, qp[0], acc);
      acc = fmaf(zv.y, qp[8], acc);
      acc = fmaf(zv.z, qp[16], acc);
      acc = fmaf(zv.w, qp[24], acc);
    }
    acc += LV[(size_t)r * 16 + k] + lvc;
    float c = tanhf(acc) * uk;
    c += __shfl_xor(c, 1);
    c += __shfl_xor(c, 2);
    c += __shfl_xor(c, 4);
    if (act && k == 0) out[eid] = 1.f / (1.f + __expf(-c));
  }
}

// ---------------- host launch ----------------
extern "C" void kernel_launch(void* const* d_in, const int* in_sizes, int n_in,
                              void* d_out, int out_size, void* d_ws, size_t ws_size,
                              hipStream_t stream) {
  const float* x     = (const float*)d_in[0];
  const int*   ei    = (const int*)d_in[1];
  const float* gamma = (const float*)d_in[2];
  const float* beta  = (const float*)d_in[3];
  const float* W1    = (const float*)d_in[4];
  const float* b1    = (const float*)d_in[5];
  const float* W2    = (const float*)d_in[6];
  const float* b2    = (const float*)d_in[7];
  const float* Wt    = (const float*)d_in[8];
  const float* V     = (const float*)d_in[9];
  const float* bt    = (const float*)d_in[10];
  const float* U     = (const float*)d_in[11];
  float* out = (float*)d_out;
  char* ws = (char*)d_ws;

  const int* row = ei;
  const int* col = ei + NEDGE;

  float* sums   = (float*)(ws + OFF_SUMS);
  float* sumsq  = (float*)(ws + OFF_SUMSQ);
  float* scale  = (float*)(ws + OFF_SCALE);
  float* shiftv = (float*)(ws + OFF_SHIFT);
  float* cshift = (float*)(ws + OFF_CSHIFT);
  int*   part   = (int*)(ws + OFF_PART);
  int*   bpref  = (int*)(ws + OFF_BPREF);
  float* W1p    = (float*)(ws + OFF_W1P);
  float* Wt2    = (float*)(ws + OFF_WT2);
  int*   deg    = (int*)(ws + OFF_DEG);
  int*   offs   = (int*)(ws + OFF_OFFS);
  int*   curs   = (int*)(ws + OFF_CURS);
  float* dinv   = (float*)(ws + OFF_DINV);
  int*   csr    = (int*)(ws + OFF_CSR);
  int*   csre   = (int*)(ws + OFF_CSRE);
  float* LV     = (float*)(ws + OFF_LV);
  float* h0     = (float*)(ws + OFF_H0);
  float* h1     = (float*)(ws + OFF_H1);
  float* z0     = (float*)(ws + OFF_Z0);
  float* zz     = (float*)(ws + OFF_Z);
  unsigned short* Q = (unsigned short*)(ws + OFF_Q);

  hipMemsetAsync(ws + OFF_SUMS, 0, 0x800, stream);        // sums+sumsq
  hipMemsetAsync(ws + OFF_DEG, 0, NNODE * 4, stream);

  bn_stats<<<256, 256, 0, stream>>>(x, sums, sumsq);
  count_deg<<<1563, 256, 0, stream>>>(col, deg);
  bn_finalize<<<1, 256, 0, stream>>>(sums, sumsq, gamma, beta, scale, shiftv);
  make_w1p<<<128, 256, 0, stream>>>(W1, scale, W1p);
  make_cshift<<<1, 128, 0, stream>>>(W1, shiftv, cshift);
  make_wt2<<<128, 256, 0, stream>>>(Wt, Wt2);

  scan_a<<<49, 1024, 0, stream>>>(deg, offs, part, dinv);
  scan_b<<<1, 64, 0, stream>>>(part, bpref, offs);
  scan_c<<<49, 1024, 0, stream>>>(offs, bpref, curs);
  fill_csr<<<1563, 256, 0, stream>>>(row, col, curs, csr, csre);

  // encode:  h0 = (xn@W1 + cshift)*dinv  -> agg -> h1 ;  z0 = (h1@W2)*dinv -> agg -> zz
  gemm_tiled<64, 128, 32, 4, 8, false><<<dim3(782, 1), 256, 0, stream>>>(x, W1p, h0, cshift, dinv, NNODE, 256, 128);
  agg_kernel<128, true><<<25000, 256, 0, stream>>>(h0, csr, offs, dinv, b1, h1);
  gemm_tiled<64, 64, 32, 4, 4, false><<<dim3(782, 1), 256, 0, stream>>>(h1, W2, z0, nullptr, dinv, NNODE, 128, 64);
  agg_kernel<64, false><<<12500, 256, 0, stream>>>(z0, csr, offs, dinv, b2, zz);

  // decode precompute
  gemm_tiled<64, 128, 32, 4, 8, true><<<dim3(782, 4), 256, 0, stream>>>(zz, Wt2, Q, nullptr, nullptr, NNODE, 64, 512);
  lv_kernel<<<3125, 256, 0, stream>>>(zz, V, LV);

  // per-edge decode
  decode_kernel<<<12500, 256, 0, stream>>>(csr, csre, offs, zz, Q, LV, bt, U, out);
}

// Round 4
// 464.477 us; speedup vs baseline: 1.2892x; 1.1424x over previous
//
#include <hip/hip_runtime.h>

// Problem constants
#define NNODE 50000
#define NEDGE 400000
// IN=256, H=128, D=64, K=8

// ---------------- workspace layout (bytes) ----------------
#define OFF_SUMS    0x0000     // 256 f
#define OFF_SUMSQ   0x0400     // 256 f
#define OFF_SCALE   0x0800     // 256 f
#define OFF_SHIFT   0x0C00     // 256 f
#define OFF_CSHIFT  0x1000     // 128 f
#define OFF_PART    0x1400     // 64 i (scan partials)
#define OFF_BPREF   0x1600     // 64 i (scan block prefix)
#define OFF_W1P     0x2000     // 256*128 f   -> ends 0x22000
#define OFF_WT2     0x22000    // 64*512 f    -> ends 0x42000
#define OFF_DEG     0x42000    // 50000 i
#define OFF_OFFS    0x73000    // 50001 i
#define OFF_CURS    0xA4000    // 50000 i
#define OFF_DINV    0xD5000    // 50000 f
#define OFF_CSR     0x106000   // 400000 i (src node per sorted edge)
#define OFF_CSRE    0x290000   // 400000 i (orig edge id per sorted edge)
#define OFF_LV      0x420000   // 50000*16 f  -> ends 0x72D400
#define OFF_H0      0x800000   // 50000*128 f (25.6MB)   -> ends 0x2068000
#define OFF_BNP     OFF_H0                 // reuse (pre-gemm1): 1024*512 f partials (2MB)
#define OFF_Z0      OFF_H0                 // reuse (h0 dead): 50000*64 f
#define OFF_Z       (OFF_H0 + 0xD00000)    // 50000*64 f, ends < 0x2100000
#define OFF_H1      0x2100000  // 50000*128 f (25.6MB)
#define OFF_Q       OFF_H1                 // reuse (h1 dead): 50000*512 bf16 (51.2MB)

#define BN_NB 1024             // stage-1 blocks

static __device__ __forceinline__ unsigned short f32_to_bf16(float f) {
  unsigned int u = __float_as_uint(f);
  u += 0x7fffu + ((u >> 16) & 1u);          // round-to-nearest-even
  return (unsigned short)(u >> 16);
}

// ---------------- BatchNorm statistics: two-stage, no atomics ----------------
// Stage 1: 1024 blocks; wave w reads whole rows (float4/lane); block writes 512 partials.
__global__ __launch_bounds__(256) void bn_stats1(const float* __restrict__ x,
                                                 float* __restrict__ P) {
  __shared__ float4 ls[4][64];
  __shared__ float4 lq[4][64];
  const int b = blockIdx.x, t = threadIdx.x;
  const int w = t >> 6, l = t & 63;
  const int rows = (NNODE + BN_NB - 1) / BN_NB;     // 49
  const int r0 = b * rows;
  const int r1 = min(NNODE, r0 + rows);
  float4 s = make_float4(0.f, 0.f, 0.f, 0.f);
  float4 q = make_float4(0.f, 0.f, 0.f, 0.f);
  for (int r = r0 + w; r < r1; r += 4) {
    float4 v = *(const float4*)(x + (size_t)r * 256 + l * 4);
    s.x += v.x; s.y += v.y; s.z += v.z; s.w += v.w;
    q.x = fmaf(v.x, v.x, q.x); q.y = fmaf(v.y, v.y, q.y);
    q.z = fmaf(v.z, v.z, q.z); q.w = fmaf(v.w, v.w, q.w);
  }
  ls[w][l] = s; lq[w][l] = q;
  __syncthreads();
  if (t < 64) {
    float4 s0 = ls[0][t], s1 = ls[1][t], s2 = ls[2][t], s3 = ls[3][t];
    float4 q0 = lq[0][t], q1 = lq[1][t], q2 = lq[2][t], q3 = lq[3][t];
    float4 ss = make_float4((s0.x + s1.x) + (s2.x + s3.x), (s0.y + s1.y) + (s2.y + s3.y),
                            (s0.z + s1.z) + (s2.z + s3.z), (s0.w + s1.w) + (s2.w + s3.w));
    float4 qq = make_float4((q0.x + q1.x) + (q2.x + q3.x), (q0.y + q1.y) + (q2.y + q3.y),
                            (q0.z + q1.z) + (q2.z + q3.z), (q0.w + q1.w) + (q2.w + q3.w));
    *(float4*)(P + (size_t)b * 512 + t * 4)       = ss;
    *(float4*)(P + (size_t)b * 512 + 256 + t * 4) = qq;
  }
}

// Stage 2: block c reduces column c of P[BN_NB][512]; c<256 -> sums, else sumsq.
__global__ __launch_bounds__(256) void bn_stats2(const float* __restrict__ P,
                                                 float* __restrict__ sums,
                                                 float* __restrict__ sumsq) {
  __shared__ float red[256];
  const int c = blockIdx.x, t = threadIdx.x;
  float s = 0.f;
  for (int i = t; i < BN_NB; i += 256) s += P[(size_t)i * 512 + c];
  red[t] = s;
  __syncthreads();
  if (t < 128) red[t] += red[t + 128];
  __syncthreads();
  if (t < 64) {
    float v = red[t] + red[t + 64];
    v += __shfl_down(v, 32);
    v += __shfl_down(v, 16);
    v += __shfl_down(v, 8);
    v += __shfl_down(v, 4);
    v += __shfl_down(v, 2);
    v += __shfl_down(v, 1);
    if (t == 0) {
      if (c < 256) sums[c] = v; else sumsq[c - 256] = v;
    }
  }
}

__global__ void bn_finalize(const float* __restrict__ sums, const float* __restrict__ sumsq,
                            const float* __restrict__ gamma, const float* __restrict__ beta,
                            float* __restrict__ scale, float* __restrict__ shift) {
  const int i = threadIdx.x;                 // 256 threads
  float mean = sums[i] * (1.f / NNODE);
  float var  = sumsq[i] * (1.f / NNODE) - mean * mean;
  float sc   = rsqrtf(var + 1e-5f) * gamma[i];
  scale[i] = sc;
  shift[i] = beta[i] - mean * sc;
}

__global__ void make_w1p(const float* __restrict__ W1, const float* __restrict__ scale,
                         float* __restrict__ W1p) {
  const int idx = blockIdx.x * 256 + threadIdx.x;   // 32768
  W1p[idx] = scale[idx >> 7] * W1[idx];             // 128 cols
}

__global__ void make_cshift(const float* __restrict__ W1, const float* __restrict__ shift,
                            float* __restrict__ cshift) {
  const int j = threadIdx.x;                 // 128 threads
  float s = 0.f;
  for (int i = 0; i < 256; ++i) s += shift[i] * W1[i * 128 + j];
  cshift[j] = s;
}

// Wt[d][c][k] -> Wt2[c][d*8+k]  (B matrix for the q-GEMM)
__global__ void make_wt2(const float* __restrict__ Wt, float* __restrict__ Wt2) {
  const int idx = blockIdx.x * 256 + threadIdx.x;   // 32768
  const int d = idx >> 9, ck = idx & 511;
  const int c = ck >> 3, k = ck & 7;
  Wt2[c * 512 + d * 8 + k] = Wt[idx];
}

// ---------------- degree / CSR build ----------------
__global__ __launch_bounds__(256) void count_deg(const int* __restrict__ col, int* __restrict__ deg) {
  const int e = blockIdx.x * 256 + threadIdx.x;
  if (e < NEDGE) atomicAdd(&deg[col[e]], 1);
}

__global__ __launch_bounds__(1024) void scan_a(const int* __restrict__ deg, int* __restrict__ offs,
                                               int* __restrict__ partials, float* __restrict__ dinv) {
  __shared__ int buf[1024];
  const int t = threadIdx.x;
  const int i = blockIdx.x * 1024 + t;
  const int v = (i < NNODE) ? deg[i] : 0;
  buf[t] = v;
  __syncthreads();
  for (int off = 1; off < 1024; off <<= 1) {
    int a = (t >= off) ? buf[t - off] : 0;
    __syncthreads();
    buf[t] += a;
    __syncthreads();
  }
  if (i < NNODE) {
    offs[i] = buf[t] - v;                     // block-local exclusive
    dinv[i] = rsqrtf((float)(v + 1));         // +1 self loop
  }
  if (t == 1023) partials[blockIdx.x] = buf[t];
}

__global__ void scan_b(const int* __restrict__ partials, int* __restrict__ bpref,
                       int* __restrict__ offs) {
  if (threadIdx.x == 0) {
    int run = 0;
    for (int b = 0; b < 49; ++b) { bpref[b] = run; run += partials[b]; }
    offs[NNODE] = run;                        // == NEDGE
  }
}

__global__ __launch_bounds__(1024) void scan_c(int* __restrict__ offs, const int* __restrict__ bpref,
                                               int* __restrict__ cursor) {
  const int i = blockIdx.x * 1024 + threadIdx.x;
  if (i < NNODE) {
    int o = offs[i] + bpref[blockIdx.x];
    offs[i] = o;
    cursor[i] = o;
  }
}

__global__ __launch_bounds__(256) void fill_csr(const int* __restrict__ row, const int* __restrict__ col,
                                                int* __restrict__ cursor, int* __restrict__ csr_src,
                                                int* __restrict__ csr_eid) {
  const int e = blockIdx.x * 256 + threadIdx.x;
  if (e < NEDGE) {
    int c = col[e];
    int p = atomicAdd(&cursor[c], 1);
    csr_src[p] = row[e];
    csr_eid[p] = e;
  }
}

// ---------------- tiled fp32 GEMM:  C[M,Nd] = (A[M,Kd] @ B[Kd,Nd] + bias) * rowscale ----------------
template <int BM, int BN, int BK, int TM, int TN, bool BF16OUT>
__global__ __launch_bounds__(256) void gemm_tiled(const float* __restrict__ A,
                                                  const float* __restrict__ B,
                                                  void* __restrict__ Cout,
                                                  const float* __restrict__ bias,
                                                  const float* __restrict__ rowscale,
                                                  int M, int Kd, int Nd) {
  constexpr int TX = BN / TN;
  constexpr int TY = BM / TM;
  constexpr int THREADS = TX * TY;            // 256
  __shared__ __align__(16) float As[BM][BK + 4];
  __shared__ __align__(16) float Bs[BK][BN];
  const int tid = threadIdx.x;
  const int tx = tid % TX, ty = tid / TX;
  const int m0 = blockIdx.x * BM, n0 = blockIdx.y * BN;

  float acc[TM][TN];
  for (int i = 0; i < TM; ++i)
    for (int j = 0; j < TN; ++j) acc[i][j] = 0.f;

  for (int k0 = 0; k0 < Kd; k0 += BK) {
    for (int i = tid; i < (BM * BK) / 4; i += THREADS) {
      int mm = i / (BK / 4), kq = i % (BK / 4);
      int gm = m0 + mm;
      float4 v = make_float4(0.f, 0.f, 0.f, 0.f);
      if (gm < M) v = *(const float4*)(A + (size_t)gm * Kd + k0 + kq * 4);
      *(float4*)(&As[mm][kq * 4]) = v;
    }
    for (int i = tid; i < (BK * BN) / 4; i += THREADS) {
      int kk = i / (BN / 4), nq = i % (BN / 4);
      *(float4*)(&Bs[kk][nq * 4]) = *(const float4*)(B + (size_t)(k0 + kk) * Nd + n0 + nq * 4);
    }
    __syncthreads();
#pragma unroll
    for (int kk = 0; kk < BK; ++kk) {
      float a[TM], b[TN];
#pragma unroll
      for (int i = 0; i < TM; ++i) a[i] = As[ty * TM + i][kk];
#pragma unroll
      for (int j4 = 0; j4 < TN / 4; ++j4) {
        float4 bv = *(const float4*)(&Bs[kk][tx * TN + j4 * 4]);
        b[j4 * 4 + 0] = bv.x; b[j4 * 4 + 1] = bv.y; b[j4 * 4 + 2] = bv.z; b[j4 * 4 + 3] = bv.w;
      }
#pragma unroll
      for (int i = 0; i < TM; ++i)
#pragma unroll
        for (int j = 0; j < TN; ++j) acc[i][j] = fmaf(a[i], b[j], acc[i][j]);
    }
    __syncthreads();
  }

  float bv[TN];
#pragma unroll
  for (int j = 0; j < TN; ++j) bv[j] = bias ? bias[n0 + tx * TN + j] : 0.f;

#pragma unroll
  for (int i = 0; i < TM; ++i) {
    int gm = m0 + ty * TM + i;
    if (gm >= M) continue;
    const float rs = rowscale ? rowscale[gm] : 1.f;
    if constexpr (BF16OUT) {
      unsigned short* C = (unsigned short*)Cout;
      alignas(16) unsigned short tmp[TN];
#pragma unroll
      for (int j = 0; j < TN; ++j) tmp[j] = f32_to_bf16((acc[i][j] + bv[j]) * rs);
      if constexpr (TN == 8) {
        *(uint4*)(C + (size_t)gm * Nd + n0 + tx * TN) = *(const uint4*)tmp;
      } else {
#pragma unroll
        for (int j = 0; j < TN; ++j) C[(size_t)gm * Nd + n0 + tx * TN + j] = tmp[j];
      }
    } else {
      float* C = (float*)Cout;
#pragma unroll
      for (int j4 = 0; j4 < TN / 4; ++j4) {
        float4 v;
        v.x = (acc[i][j4 * 4 + 0] + bv[j4 * 4 + 0]) * rs;
        v.y = (acc[i][j4 * 4 + 1] + bv[j4 * 4 + 1]) * rs;
        v.z = (acc[i][j4 * 4 + 2] + bv[j4 * 4 + 2]) * rs;
        v.w = (acc[i][j4 * 4 + 3] + bv[j4 * 4 + 3]) * rs;
        *(float4*)(C + (size_t)gm * Nd + n0 + tx * TN + j4 * 4) = v;
      }
    }
  }
}

// ---------------- GCN aggregation over pre-scaled features ----------------
// hs[r] = (feature row r) * dinv[r];  out[v] = dinv[v]*(sum_in hs[r] + hs[v]) + b
// 4-wide predicated unroll: 4 independent accumulators keep 4 row-gathers in flight.
template <int F, bool LEAKY>
__global__ __launch_bounds__(256) void agg_kernel(const float* __restrict__ hs,
                                                  const int* __restrict__ csr_src,
                                                  const int* __restrict__ offs,
                                                  const float* __restrict__ dinv,
                                                  const float* __restrict__ bias,
                                                  float* __restrict__ out) {
  constexpr int NPB = 256 / F;
  const int vth = blockIdx.x * NPB + threadIdx.x / F;
  const int v = __builtin_amdgcn_readfirstlane(vth);   // wave-uniform in both configs
  const int f = threadIdx.x % F;
  const float dv = dinv[v];
  const int j0 = offs[v], j1 = offs[v + 1];

  float a0 = hs[(size_t)v * F + f];           // self loop (pre-scaled by dinv[v])
  float a1 = 0.f, a2 = 0.f, a3 = 0.f;

  for (int jb = j0; jb < j1; jb += 4) {
    const int jm = j1 - 1;
    const int r0 = csr_src[jb];
    const int r1 = csr_src[min(jb + 1, jm)];
    const int r2 = csr_src[min(jb + 2, jm)];
    const int r3 = csr_src[min(jb + 3, jm)];
    const float w1 = (jb + 1 <= jm) ? 1.f : 0.f;
    const float w2 = (jb + 2 <= jm) ? 1.f : 0.f;
    const float w3 = (jb + 3 <= jm) ? 1.f : 0.f;
    a0 += hs[(size_t)r0 * F + f];
    a1 = fmaf(w1, hs[(size_t)r1 * F + f], a1);
    a2 = fmaf(w2, hs[(size_t)r2 * F + f], a2);
    a3 = fmaf(w3, hs[(size_t)r3 * F + f], a3);
  }

  float o = ((a0 + a1) + (a2 + a3)) * dv + bias[f];
  if (LEAKY) o = (o >= 0.f) ? o : 0.1f * o;
  out[(size_t)v * F + f] = o;
}

// ---------------- per-node linear terms: LV[v][k]=z_v.V[k,:64], LV[v][8+k]=z_v.V[k,64:] ----------------
__global__ __launch_bounds__(256) void lv_kernel(const float* __restrict__ z,
                                                 const float* __restrict__ V,
                                                 float* __restrict__ LV) {
  const int idx = blockIdx.x * 256 + threadIdx.x;     // 800000
  if (idx >= NNODE * 16) return;
  const int v = idx >> 4, kk = idx & 15;
  const float* vr = V + (kk & 7) * 128 + ((kk & 8) ? 64 : 0);
  const float* zr = z + (size_t)v * 64;
  float s = 0.f;
#pragma unroll
  for (int d4 = 0; d4 < 16; ++d4) {
    float4 zv = *(const float4*)(zr + d4 * 4);
    float4 vv = *(const float4*)(vr + d4 * 4);
    s += zv.x * vv.x + zv.y * vv.y + zv.z * vv.z + zv.w * vv.w;
  }
  LV[idx] = s;
}

// ---------------- decode: wave per dst node; 8 edges x 8 k-lanes ----------------
__global__ __launch_bounds__(256) void decode_kernel(const int* __restrict__ csr_src,
                                                     const int* __restrict__ csr_eid,
                                                     const int* __restrict__ offs,
                                                     const float* __restrict__ z,
                                                     const unsigned short* __restrict__ Q,  // bf16 bits
                                                     const float* __restrict__ LV,
                                                     const float* __restrict__ bt,
                                                     const float* __restrict__ U,
                                                     float* __restrict__ out) {
  __shared__ float qs[4][512];
  const int w = threadIdx.x >> 6, lane = threadIdx.x & 63;
  const int v = blockIdx.x * 4 + w;                 // 12500*4 == 50000 exactly

  { // stage q_v (bf16 -> f32) into LDS: lane loads 16B = 8 bf16
    const unsigned short* qrow = Q + (size_t)v * 512;
    union { uint4 r; unsigned short u[8]; } uu;
    uu.r = *(const uint4*)(qrow + lane * 8);
#pragma unroll
    for (int j = 0; j < 8; ++j)
      qs[w][lane * 8 + j] = __uint_as_float(((unsigned int)uu.u[j]) << 16);
  }
  __syncthreads();

  const int g = lane >> 3, k = lane & 7;
  const float uk = U[k];
  const float lvc = LV[(size_t)v * 16 + 8 + k] + bt[k];
  const int j0 = offs[v], j1 = offs[v + 1];

  for (int jb = j0; jb < j1; jb += 8) {
    const int j = jb + g;
    const bool act = (j < j1);
    const int r = act ? csr_src[j] : 0;
    const int eid = act ? csr_eid[j] : 0;
    const float4* zr = (const float4*)(z + (size_t)r * 64);
    float acc = 0.f;
#pragma unroll
    for (int d4 = 0; d4 < 16; ++d4) {
      float4 zv = zr[d4];
      const float* qp = &qs[w][d4 * 32 + k];
      acc = fmaf(zv.x, qp[0], acc);
      acc = fmaf(zv.y, qp[8], acc);
      acc = fmaf(zv.z, qp[16], acc);
      acc = fmaf(zv.w, qp[24], acc);
    }
    acc += LV[(size_t)r * 16 + k] + lvc;
    float c = tanhf(acc) * uk;
    c += __shfl_xor(c, 1);
    c += __shfl_xor(c, 2);
    c += __shfl_xor(c, 4);
    if (act && k == 0) out[eid] = 1.f / (1.f + __expf(-c));
  }
}

// ---------------- host launch ----------------
extern "C" void kernel_launch(void* const* d_in, const int* in_sizes, int n_in,
                              void* d_out, int out_size, void* d_ws, size_t ws_size,
                              hipStream_t stream) {
  const float* x     = (const float*)d_in[0];
  const int*   ei    = (const int*)d_in[1];
  const float* gamma = (const float*)d_in[2];
  const float* beta  = (const float*)d_in[3];
  const float* W1    = (const float*)d_in[4];
  const float* b1    = (const float*)d_in[5];
  const float* W2    = (const float*)d_in[6];
  const float* b2    = (const float*)d_in[7];
  const float* Wt    = (const float*)d_in[8];
  const float* V     = (const float*)d_in[9];
  const float* bt    = (const float*)d_in[10];
  const float* U     = (const float*)d_in[11];
  float* out = (float*)d_out;
  char* ws = (char*)d_ws;

  const int* row = ei;
  const int* col = ei + NEDGE;

  float* sums   = (float*)(ws + OFF_SUMS);
  float* sumsq  = (float*)(ws + OFF_SUMSQ);
  float* scale  = (float*)(ws + OFF_SCALE);
  float* shiftv = (float*)(ws + OFF_SHIFT);
  float* cshift = (float*)(ws + OFF_CSHIFT);
  int*   part   = (int*)(ws + OFF_PART);
  int*   bpref  = (int*)(ws + OFF_BPREF);
  float* W1p    = (float*)(ws + OFF_W1P);
  float* Wt2    = (float*)(ws + OFF_WT2);
  int*   deg    = (int*)(ws + OFF_DEG);
  int*   offs   = (int*)(ws + OFF_OFFS);
  int*   curs   = (int*)(ws + OFF_CURS);
  float* dinv   = (float*)(ws + OFF_DINV);
  int*   csr    = (int*)(ws + OFF_CSR);
  int*   csre   = (int*)(ws + OFF_CSRE);
  float* LV     = (float*)(ws + OFF_LV);
  float* bnp    = (float*)(ws + OFF_BNP);
  float* h0     = (float*)(ws + OFF_H0);
  float* h1     = (float*)(ws + OFF_H1);
  float* z0     = (float*)(ws + OFF_Z0);
  float* zz     = (float*)(ws + OFF_Z);
  unsigned short* Q = (unsigned short*)(ws + OFF_Q);

  hipMemsetAsync(ws + OFF_DEG, 0, NNODE * 4, stream);

  bn_stats1<<<BN_NB, 256, 0, stream>>>(x, bnp);
  count_deg<<<1563, 256, 0, stream>>>(col, deg);
  bn_stats2<<<512, 256, 0, stream>>>(bnp, sums, sumsq);
  bn_finalize<<<1, 256, 0, stream>>>(sums, sumsq, gamma, beta, scale, shiftv);
  make_w1p<<<128, 256, 0, stream>>>(W1, scale, W1p);
  make_cshift<<<1, 128, 0, stream>>>(W1, shiftv, cshift);
  make_wt2<<<128, 256, 0, stream>>>(Wt, Wt2);

  scan_a<<<49, 1024, 0, stream>>>(deg, offs, part, dinv);
  scan_b<<<1, 64, 0, stream>>>(part, bpref, offs);
  scan_c<<<49, 1024, 0, stream>>>(offs, bpref, curs);
  fill_csr<<<1563, 256, 0, stream>>>(row, col, curs, csr, csre);

  // encode:  h0 = (xn@W1 + cshift)*dinv  -> agg -> h1 ;  z0 = (h1@W2)*dinv -> agg -> zz
  gemm_tiled<64, 128, 32, 4, 8, false><<<dim3(782, 1), 256, 0, stream>>>(x, W1p, h0, cshift, dinv, NNODE, 256, 128);
  agg_kernel<128, true><<<25000, 256, 0, stream>>>(h0, csr, offs, dinv, b1, h1);
  gemm_tiled<64, 64, 32, 4, 4, false><<<dim3(782, 1), 256, 0, stream>>>(h1, W2, z0, nullptr, dinv, NNODE, 128, 64);
  agg_kernel<64, false><<<12500, 256, 0, stream>>>(z0, csr, offs, dinv, b2, zz);

  // decode precompute
  gemm_tiled<64, 128, 32, 4, 8, true><<<dim3(782, 4), 256, 0, stream>>>(zz, Wt2, Q, nullptr, nullptr, NNODE, 64, 512);
  lv_kernel<<<3125, 256, 0, stream>>>(zz, V, LV);

  // per-edge decode
  decode_kernel<<<12500, 256, 0, stream>>>(csr, csre, offs, zz, Q, LV, bt, U, out);
}